// Round 1
// baseline (63.788 us; speedup 1.0000x reference)
//
#include <hip/hip_runtime.h>
#include <math.h>

// ---------------------------------------------------------------------------
// FashionNetLoss: 3-scale YOLO-ish loss.
// Key facts exploited:
//  * obj focal loss is a mean over ALL cells, but target is 0 except at the
//    512 occupied cells per scale -> compute sum of focal(x,0) over all cells,
//    then per-target correction focal(x,t)-focal(x,0).
//  * box & cls losses only involve the 512 occupied cells per scale.
//  * npos == 512 per scale (targets are distinct 40-grid cells; 80/160 grids
//    map distinct 40-cells into disjoint blocks -> no collisions).
// ws layout (floats): [scale*4 + {0:focal_all, 1:box_sum, 2:cls_sum, 3:obj_corr}]
// ---------------------------------------------------------------------------

namespace {
__device__ __forceinline__ float bce_logits(float x, float t) {
    // max(x,0) - x*t + log1p(exp(-|x|))
    return fmaxf(x, 0.0f) - x * t + log1pf(expf(-fabsf(x)));
}
__device__ __forceinline__ float focal_term(float x, float t) {
    // alpha * (1-p_t)^1.5 * bce,  p_t = exp(-bce), alpha = 0.25
    float b = bce_logits(x, t);
    float pt = expf(-b);
    float om = fmaxf(1.0f - pt, 0.0f);
    return 0.25f * om * sqrtf(om) * b;
}
} // namespace

// Zero the 16-float accumulator every call (ws is poisoned / not re-poisoned).
__global__ void fnl_zero_ws(float* __restrict__ ws) {
    if (threadIdx.x < 16) ws[threadIdx.x] = 0.0f;
}

// Sum of focal(x, 0) over every objectness logit of all 3 scales.
// float4 elements: scale0 = 204800 (hw4=6400), scale1 = 51200 (hw4=1600),
// scale2 = 12800 (hw4=400). Boundaries are multiples of 256 -> each block is
// entirely within one scale. Grid = 1050 blocks x 256.
__global__ void __launch_bounds__(256) fnl_obj_focal(
    const float* __restrict__ p0, const float* __restrict__ p1,
    const float* __restrict__ p2, float* __restrict__ ws) {
    int i = blockIdx.x * 256 + threadIdx.x;
    const float* p;
    int hw4, scale, idx;
    if (i < 204800)      { p = p0; hw4 = 6400; scale = 0; idx = i; }
    else if (i < 256000) { p = p1; hw4 = 1600; scale = 1; idx = i - 204800; }
    else                 { p = p2; hw4 = 400;  scale = 2; idx = i - 256000; }
    int b = idx / hw4;
    int pos4 = idx - b * hw4;
    int hw = hw4 * 4;
    const float4* src =
        reinterpret_cast<const float4*>(p + (size_t)b * 18 * hw + (size_t)4 * hw);
    float4 x = src[pos4];
    float v = focal_term(x.x, 0.0f) + focal_term(x.y, 0.0f) +
              focal_term(x.z, 0.0f) + focal_term(x.w, 0.0f);

    // wave64 butterfly-free down-reduce, then cross-wave via LDS
    for (int off = 32; off; off >>= 1) v += __shfl_down(v, off);
    __shared__ float sm[4];
    if ((threadIdx.x & 63) == 0) sm[threadIdx.x >> 6] = v;
    __syncthreads();
    if (threadIdx.x == 0)
        atomicAdd(&ws[scale * 4 + 0], sm[0] + sm[1] + sm[2] + sm[3]);
}

// One thread per target; loops over the 3 scales. Computes CIoU (box loss),
// obj-focal correction at the occupied cell, and 13-class BCE sum.
__global__ void __launch_bounds__(256) fnl_targets(
    const float* __restrict__ p0, const float* __restrict__ p1,
    const float* __restrict__ p2, const float* __restrict__ tg,
    float* __restrict__ ws) {
    int t = blockIdx.x * 256 + threadIdx.x;
    if (t >= 512) return;
    const float bi  = tg[t * 6 + 0];
    const float clf = tg[t * 6 + 1];
    const float cx  = tg[t * 6 + 2];
    const float cy  = tg[t * 6 + 3];
    const float w   = tg[t * 6 + 4];
    const float h   = tg[t * 6 + 5];
    const int b = (int)bi;
    const int cls = (int)clf;

    const float* ps[3] = {p0, p1, p2};
    const int gss[3] = {160, 80, 40};

    for (int s = 0; s < 3; ++s) {
        const int gs = gss[s];
        const float fgs = (float)gs;
        float cxs = cx * fgs, cys = cy * fgs;
        int gi = (int)floorf(cxs); gi = min(max(gi, 0), gs - 1);
        int gj = (int)floorf(cys); gj = min(max(gj, 0), gs - 1);
        const float tx = cxs - (float)gi;
        const float ty = cys - (float)gj;
        const float tw = w * fgs;
        const float th = h * fgs;

        const int hw = gs * gs;
        const float* base = ps[s] + (size_t)b * 18 * hw + (size_t)gj * gs + gi;
        float pr[18];
        #pragma unroll
        for (int ch = 0; ch < 18; ++ch) pr[ch] = base[(size_t)ch * hw];

        const float px = 1.0f / (1.0f + expf(-pr[0]));
        const float py = 1.0f / (1.0f + expf(-pr[1]));
        const float pw = pr[2];
        const float ph = pr[3];

        // ---- CIoU (exact replication of reference formula, f32) ----
        const float eps = 1e-7f;
        float px1 = px - pw * 0.5f, px2 = px + pw * 0.5f;
        float py1 = py - ph * 0.5f, py2 = py + ph * 0.5f;
        float tx1 = tx - tw * 0.5f, tx2 = tx + tw * 0.5f;
        float ty1 = ty - th * 0.5f, ty2 = ty + th * 0.5f;
        float iw = fmaxf(fminf(px2, tx2) - fmaxf(px1, tx1), 0.0f);
        float ih = fmaxf(fminf(py2, ty2) - fmaxf(py1, ty1), 0.0f);
        float inter = iw * ih;
        float uni = pw * ph + tw * th - inter + eps;
        float iou = inter / uni;
        float ew = fmaxf(fmaxf(px2, tx2) - fminf(px1, tx1), 0.0f);
        float eh = fmaxf(fmaxf(py2, ty2) - fminf(py1, ty1), 0.0f);
        float c2 = ew * ew + eh * eh + eps;
        float rho2 = (px - tx) * (px - tx) + (py - ty) * (py - ty);
        const float four_over_pi2 = 0.405284734569351085775517852f;
        float dat = atanf(tw / (th + eps)) - atanf(pw / (ph + eps));
        float v = four_over_pi2 * dat * dat;
        float alpha = v / (1.0f - iou + v + eps);
        float ciou = iou - (rho2 / c2 + v * alpha);
        // ------------------------------------------------------------

        float box = 1.0f - ciou;
        float tobj = fmaxf(ciou, 0.0f);
        float corr = focal_term(pr[4], tobj) - focal_term(pr[4], 0.0f);
        float clsum = 0.0f;
        #pragma unroll
        for (int k = 0; k < 13; ++k) {
            float tc = (k == cls) ? 0.95f : 0.0f;
            clsum += bce_logits(pr[5 + k], tc);
        }
        atomicAdd(&ws[s * 4 + 1], box);
        atomicAdd(&ws[s * 4 + 2], clsum);
        atomicAdd(&ws[s * 4 + 3], corr);
    }
}

__global__ void fnl_finalize(const float* __restrict__ ws, float* __restrict__ out) {
    if (threadIdx.x != 0 || blockIdx.x != 0) return;
    const float cells[3] = {819200.0f, 204800.0f, 51200.0f};
    const float npos = 512.0f;
    float lb = 0.0f, lo = 0.0f, lc = 0.0f;
    for (int s = 0; s < 3; ++s) {
        lb += ws[s * 4 + 1] / npos;
        lo += (ws[s * 4 + 0] + ws[s * 4 + 3]) / cells[s];
        lc += ws[s * 4 + 2] / (npos * 13.0f);
    }
    out[0] = 5.0f * lb + 1.0f * lo + 0.5f * lc;
    out[1] = lb;
    out[2] = lo;
    out[3] = lc;
}

extern "C" void kernel_launch(void* const* d_in, const int* in_sizes, int n_in,
                              void* d_out, int out_size, void* d_ws, size_t ws_size,
                              hipStream_t stream) {
    const float* p0 = (const float*)d_in[0];
    const float* p1 = (const float*)d_in[1];
    const float* p2 = (const float*)d_in[2];
    const float* tg = (const float*)d_in[3];
    float* ws = (float*)d_ws;
    float* out = (float*)d_out;

    fnl_zero_ws<<<1, 64, 0, stream>>>(ws);
    fnl_obj_focal<<<1050, 256, 0, stream>>>(p0, p1, p2, ws);
    fnl_targets<<<2, 256, 0, stream>>>(p0, p1, p2, tg, ws);
    fnl_finalize<<<1, 64, 0, stream>>>(ws, out);
}

// Round 2
// 32.854 us; speedup vs baseline: 1.9416x; 1.9416x over previous
//
#include <hip/hip_runtime.h>
#include <math.h>

// ---------------------------------------------------------------------------
// FashionNetLoss: 3-scale YOLO-ish loss.
//  * obj focal loss is a mean over ALL cells, but target is 0 except at the
//    512 occupied cells per scale -> sum focal(x,0) over all cells, then a
//    per-target correction focal(x,t)-focal(x,0).
//  * box & cls losses only involve the 512 occupied cells per scale.
//  * npos == 512 per scale (targets are distinct 40-grid cells; finer grids
//    map them to distinct cells too).
// ws layout (floats): [scale*4 + {0:focal_all, 1:box_sum, 2:cls_sum, 3:obj_corr}]
//
// R1: fnl_targets was 50us at 0.07% occupancy (2 blocks, latency-bound on
// 54 scattered loads/thread). Now: one thread per (target,scale), fused into
// the focal-sweep kernel as 6 extra blocks so gather latency hides under the
// streaming blocks. 3 launches total.
// ---------------------------------------------------------------------------

namespace {
__device__ __forceinline__ float bce_logits(float x, float t) {
    return fmaxf(x, 0.0f) - x * t + log1pf(expf(-fabsf(x)));
}
__device__ __forceinline__ float focal_term(float x, float t) {
    float b = bce_logits(x, t);
    float pt = expf(-b);
    float om = fmaxf(1.0f - pt, 0.0f);
    return 0.25f * om * sqrtf(om) * b;   // alpha=0.25, gamma=1.5
}
} // namespace

__global__ void fnl_zero_ws(float* __restrict__ ws) {
    if (threadIdx.x < 16) ws[threadIdx.x] = 0.0f;
}

// Blocks [0,1050): sum of focal(x,0) over every objectness logit (float4).
// Blocks [1050,1056): one thread per (target,scale) pair (1536 total).
__global__ void __launch_bounds__(256) fnl_main(
    const float* __restrict__ p0, const float* __restrict__ p1,
    const float* __restrict__ p2, const float* __restrict__ tg,
    float* __restrict__ ws) {
    __shared__ float sm[4];

    if (blockIdx.x < 1050) {
        // ---------------- focal(x,0) sweep over channel-4 planes ----------
        int i = blockIdx.x * 256 + threadIdx.x;
        const float* p;
        int hw4, scale, idx;
        if (i < 204800)      { p = p0; hw4 = 6400; scale = 0; idx = i; }
        else if (i < 256000) { p = p1; hw4 = 1600; scale = 1; idx = i - 204800; }
        else                 { p = p2; hw4 = 400;  scale = 2; idx = i - 256000; }
        int b = idx / hw4;
        int pos4 = idx - b * hw4;
        int hw = hw4 * 4;
        const float4* src =
            reinterpret_cast<const float4*>(p + (size_t)b * 18 * hw + (size_t)4 * hw);
        float4 x = src[pos4];
        float v = focal_term(x.x, 0.0f) + focal_term(x.y, 0.0f) +
                  focal_term(x.z, 0.0f) + focal_term(x.w, 0.0f);

        for (int off = 32; off; off >>= 1) v += __shfl_down(v, off);
        if ((threadIdx.x & 63) == 0) sm[threadIdx.x >> 6] = v;
        __syncthreads();
        if (threadIdx.x == 0)
            atomicAdd(&ws[scale * 4 + 0], sm[0] + sm[1] + sm[2] + sm[3]);
        return;
    }

    // ---------------- per-(target,scale) losses ---------------------------
    int gid = (blockIdx.x - 1050) * 256 + threadIdx.x;  // [0,1536)
    int s = gid >> 9;         // scale; wave-uniform (512 % 64 == 0)
    int t = gid & 511;        // target

    const float bi  = tg[t * 6 + 0];
    const float clf = tg[t * 6 + 1];
    const float cx  = tg[t * 6 + 2];
    const float cy  = tg[t * 6 + 3];
    const float w   = tg[t * 6 + 4];
    const float h   = tg[t * 6 + 5];
    const int b = (int)bi;
    const int cls = (int)clf;

    const float* ps[3] = {p0, p1, p2};
    const int gss[3] = {160, 80, 40};
    const int gs = gss[s];
    const float fgs = (float)gs;

    float cxs = cx * fgs, cys = cy * fgs;
    int gi = (int)floorf(cxs); gi = min(max(gi, 0), gs - 1);
    int gj = (int)floorf(cys); gj = min(max(gj, 0), gs - 1);
    const float tx = cxs - (float)gi;
    const float ty = cys - (float)gj;
    const float tw = w * fgs;
    const float th = h * fgs;

    const int hw = gs * gs;
    const float* base = ps[s] + (size_t)b * 18 * hw + (size_t)gj * gs + gi;
    float pr[18];
    #pragma unroll
    for (int ch = 0; ch < 18; ++ch) pr[ch] = base[(size_t)ch * hw];

    const float px = 1.0f / (1.0f + expf(-pr[0]));
    const float py = 1.0f / (1.0f + expf(-pr[1]));
    const float pw = pr[2];
    const float ph = pr[3];

    // ---- CIoU (exact replication of reference formula, f32) ----
    const float eps = 1e-7f;
    float px1 = px - pw * 0.5f, px2 = px + pw * 0.5f;
    float py1 = py - ph * 0.5f, py2 = py + ph * 0.5f;
    float tx1 = tx - tw * 0.5f, tx2 = tx + tw * 0.5f;
    float ty1 = ty - th * 0.5f, ty2 = ty + th * 0.5f;
    float iw = fmaxf(fminf(px2, tx2) - fmaxf(px1, tx1), 0.0f);
    float ih = fmaxf(fminf(py2, ty2) - fmaxf(py1, ty1), 0.0f);
    float inter = iw * ih;
    float uni = pw * ph + tw * th - inter + eps;
    float iou = inter / uni;
    float ew = fmaxf(fmaxf(px2, tx2) - fminf(px1, tx1), 0.0f);
    float eh = fmaxf(fmaxf(py2, ty2) - fminf(py1, ty1), 0.0f);
    float c2 = ew * ew + eh * eh + eps;
    float rho2 = (px - tx) * (px - tx) + (py - ty) * (py - ty);
    const float four_over_pi2 = 0.405284734569351085775517852f;
    float dat = atanf(tw / (th + eps)) - atanf(pw / (ph + eps));
    float v = four_over_pi2 * dat * dat;
    float alpha = v / (1.0f - iou + v + eps);
    float ciou = iou - (rho2 / c2 + v * alpha);
    // ------------------------------------------------------------

    float box = 1.0f - ciou;
    float tobj = fmaxf(ciou, 0.0f);
    float corr = focal_term(pr[4], tobj) - focal_term(pr[4], 0.0f);
    float clsum = 0.0f;
    #pragma unroll
    for (int k = 0; k < 13; ++k) {
        float tc = (k == cls) ? 0.95f : 0.0f;
        clsum += bce_logits(pr[5 + k], tc);
    }

    // wave-level reduce (scale-uniform within each wave), then 3 atomics/wave
    for (int off = 32; off; off >>= 1) {
        box   += __shfl_down(box, off);
        clsum += __shfl_down(clsum, off);
        corr  += __shfl_down(corr, off);
    }
    if ((threadIdx.x & 63) == 0) {
        atomicAdd(&ws[s * 4 + 1], box);
        atomicAdd(&ws[s * 4 + 2], clsum);
        atomicAdd(&ws[s * 4 + 3], corr);
    }
}

__global__ void fnl_finalize(const float* __restrict__ ws, float* __restrict__ out) {
    if (threadIdx.x != 0 || blockIdx.x != 0) return;
    const float cells[3] = {819200.0f, 204800.0f, 51200.0f};
    const float npos = 512.0f;
    float lb = 0.0f, lo = 0.0f, lc = 0.0f;
    for (int s = 0; s < 3; ++s) {
        lb += ws[s * 4 + 1] / npos;
        lo += (ws[s * 4 + 0] + ws[s * 4 + 3]) / cells[s];
        lc += ws[s * 4 + 2] / (npos * 13.0f);
    }
    out[0] = 5.0f * lb + 1.0f * lo + 0.5f * lc;
    out[1] = lb;
    out[2] = lo;
    out[3] = lc;
}

extern "C" void kernel_launch(void* const* d_in, const int* in_sizes, int n_in,
                              void* d_out, int out_size, void* d_ws, size_t ws_size,
                              hipStream_t stream) {
    const float* p0 = (const float*)d_in[0];
    const float* p1 = (const float*)d_in[1];
    const float* p2 = (const float*)d_in[2];
    const float* tg = (const float*)d_in[3];
    float* ws = (float*)d_ws;
    float* out = (float*)d_out;

    fnl_zero_ws<<<1, 64, 0, stream>>>(ws);
    fnl_main<<<1056, 256, 0, stream>>>(p0, p1, p2, tg, ws);
    fnl_finalize<<<1, 64, 0, stream>>>(ws, out);
}